// Round 8
// baseline (226.377 us; speedup 1.0000x reference)
//
#include <hip/hip_runtime.h>
#include <math.h>

constexpr int T_TOK = 16384;
constexpr int HDIM  = 2048;
constexpr int NEXP  = 64;
constexpr int TPB   = 64;            // tokens per block -> 256 blocks, 1 per CU
constexpr int NWAVE = 8;
constexpr int KPW   = HDIM / NWAVE;  // 256 k per wave
constexpr int KSTEP = 32;
constexpr int NKS   = KPW / KSTEP;   // 8 k-steps

typedef __attribute__((ext_vector_type(8))) short v8s;   // 8 bf16 (4 VGPRs)
typedef __attribute__((ext_vector_type(4))) float v4f;   // 4 fp32 acc

#define MFMA_BF16 __builtin_amdgcn_mfma_f32_16x16x32_bf16

// Dekker-style truncation split: x = h + m + l exactly to ~24 mantissa bits.
static __device__ __forceinline__ void split3(float x, unsigned short& h,
                                              unsigned short& m, unsigned short& l)
{
    unsigned u0 = __float_as_uint(x);
    h = (unsigned short)(u0 >> 16);
    float r1 = x - __uint_as_float(u0 & 0xFFFF0000u);     // exact
    unsigned u1 = __float_as_uint(r1);
    m = (unsigned short)(u1 >> 16);
    float r2 = r1 - __uint_as_float(u1 & 0xFFFF0000u);    // exact
    l = (unsigned short)(__float_as_uint(r2) >> 16);
}

static __device__ __forceinline__ void frag3(const float4& x0, const float4& x1,
                                             v8s& h, v8s& m, v8s& l)
{
    unsigned short sh, sm, sl;
    split3(x0.x, sh, sm, sl); h[0]=(short)sh; m[0]=(short)sm; l[0]=(short)sl;
    split3(x0.y, sh, sm, sl); h[1]=(short)sh; m[1]=(short)sm; l[1]=(short)sl;
    split3(x0.z, sh, sm, sl); h[2]=(short)sh; m[2]=(short)sm; l[2]=(short)sl;
    split3(x0.w, sh, sm, sl); h[3]=(short)sh; m[3]=(short)sm; l[3]=(short)sl;
    split3(x1.x, sh, sm, sl); h[4]=(short)sh; m[4]=(short)sm; l[4]=(short)sl;
    split3(x1.y, sh, sm, sl); h[5]=(short)sh; m[5]=(short)sm; l[5]=(short)sl;
    split3(x1.z, sh, sm, sl); h[6]=(short)sh; m[6]=(short)sm; l[6]=(short)sl;
    split3(x1.w, sh, sm, sl); h[7]=(short)sh; m[7]=(short)sm; l[7]=(short)sl;
}

// swizzled expert column for the LDS reduction buffer (breaks 4-way write conflicts)
static __device__ __forceinline__ int swz_e(int tok, int e) {
    return e ^ (((tok >> 2) & 1) << 4);
}

// async global->LDS, 16B per lane, dest = wave-uniform base + lane*16
static __device__ __forceinline__ void glds16(const float* g, float* l)
{
    __builtin_amdgcn_global_load_lds((const __attribute__((address_space(1))) void*)g,
                                     (__attribute__((address_space(3))) void*)l,
                                     16, 0, 0);
}

// ---------------------------------------------------------------------------
// Prep kernel (R4/R5 proven, absmax-clean): split W and pack in MFMA-fragment
// order. chunk = ((wv*8 + ks)*12 + nt*3 + plane)*64 + lane, 16 B per lane.
// Main-kernel B loads are base + lane*16: perfectly coalesced 1 KB.
// ---------------------------------------------------------------------------
__global__ __launch_bounds__(256)
void pack_w_kernel(const float* __restrict__ W, short* __restrict__ P)
{
    const int tid = blockIdx.x * 256 + threadIdx.x;   // 0..49151
    const int l   = tid & 63;
    int g = tid >> 6;
    const int p  = g % 3;  g /= 3;
    const int nt = g % 4;  g /= 4;
    const int ks = g % 8;
    const int wv = g / 8;
    const int r16 = l & 15, q = l >> 4;
    const float* src = W + (size_t)(nt * 16 + r16) * HDIM + wv * KPW + ks * KSTEP + q * 8;
    float4 x0 = *(const float4*)src;
    float4 x1 = *(const float4*)(src + 4);
    v8s h, m, lo;
    frag3(x0, x1, h, m, lo);
    v8s outv = (p == 0) ? h : (p == 1) ? m : lo;
    *(v8s*)(P + (size_t)tid * 8) = outv;
}

// ---------------------------------------------------------------------------
// Main kernel: R0 structure + coalesced memory paths.
//  - R0 numeric tree verbatim (frag3 per mt, 6-product order, k-split acc,
//    4-slot 2-phase reduction) -> absmax must be exactly 0.0078125.
//  - A: wave-private LDS dbuf slice (2x8 KB), staged by 8x global_load_lds
//    (16 B/lane, linear dest; chunk-swizzle pre-applied to the GLOBAL source).
//    Wave reads only its own slice -> NO barrier in the K-loop.
//  - B: packed bf16 planes, 12 coalesced 1 KB loads/k-step, prefetched one
//    full k-step ahead in registers.
//  - counted s_waitcnt vmcnt(20) (= 12 B + 8 glds in flight), never 0 in-loop.
// ---------------------------------------------------------------------------
__global__ __launch_bounds__(512, 2)
void moe_router_mfma(const float* __restrict__ X,
                     const short* __restrict__ Pw,
                     const float* __restrict__ Bg,
                     float* __restrict__ out)
{
    __shared__ __align__(16) float smem[32768];  // 128 KiB: 8 waves x 2 x 8 KB
                                                 // epilogue red[4][64][64] aliases [0..16384)

    const int tid  = threadIdx.x;
    const int lane = tid & 63;
    const int wv   = tid >> 6;             // wave id = k-slice
    const int r16  = lane & 15;
    const int q    = lane >> 4;            // quad id (k-chunk selector)
    const int tok0 = blockIdx.x * TPB;

    // ---- A staging source (pre-swizzled global address, rule 21):
    //      glds j writes rows j*8..j*8+7 of this wave's k-window; lane l covers
    //      (row = j*8 + l/8, phys chunk = l%8).  phys holds logical chunk
    //      (l%8) ^ (row&7), and (row&7) == l/8 for every j.
    const int srow8 = lane >> 3;                 // 0..7
    const int schk  = (lane & 7) ^ srow8;        // swizzled source chunk
    const float* gA = X + (size_t)(tok0 + srow8) * HDIM + wv * KPW + schk * 4;
    float* ldsW = &smem[wv * 4096];              // wave slice (two 2048-float bufs)

    // ---- A read offsets: row = 16*mt + r16, logical chunks 2q, 2q+1,
    //      phys = logical ^ (r16&7)
    const int s  = r16 & 7;
    const int p0 = ((2 * q)     ^ s) * 4;
    const int p1 = ((2 * q + 1) ^ s) * 4;
    const int rrow = r16 * 32;

    // ---- B packed fragment pointer
    const short* pBw = Pw + (size_t)(wv * 8) * 12 * 512 + lane * 8;

    v4f acc[4][4];
#pragma unroll
    for (int mt = 0; mt < 4; ++mt)
#pragma unroll
        for (int nt = 0; nt < 4; ++nt)
            acc[mt][nt] = (v4f){0.f, 0.f, 0.f, 0.f};

    // ---- prologue: B(0) into Bc, stage A window ks=0 into buf0
    v8s Bc[12];
#pragma unroll
    for (int c = 0; c < 12; ++c) Bc[c] = *(const v8s*)(pBw + c * 512);
#pragma unroll
    for (int j = 0; j < 8; ++j)
        glds16(gA + (size_t)j * 8 * HDIM, ldsW + j * 256);

#pragma unroll
    for (int ks = 0; ks < NKS; ++ks) {
        const float* bufp = ldsW + (ks & 1) * 2048;

        // ---- issue next k-step: 12 B loads then 8 glds (20 VMEM ops)
        v8s Bn[12];
        if (ks < NKS - 1) {
            const short* pBk = pBw + (size_t)(ks + 1) * 6144;
#pragma unroll
            for (int c = 0; c < 12; ++c) Bn[c] = *(const v8s*)(pBk + c * 512);
            float* dst = ldsW + ((ks + 1) & 1) * 2048;
            const float* srcb = gA + (ks + 1) * KSTEP;
#pragma unroll
            for (int j = 0; j < 8; ++j)
                glds16(srcb + (size_t)j * 8 * HDIM, dst + j * 256);
            // allow this iteration's 20 ops to stay in flight; everything
            // older (incl. the glds feeding bufp) must have landed.
            asm volatile("s_waitcnt vmcnt(20)" ::: "memory");
        } else {
            asm volatile("s_waitcnt vmcnt(0)" ::: "memory");
        }
        __builtin_amdgcn_sched_barrier(0);

        // ---- compute (R0 numeric tree): per mt, ds_read + frag3 + 24 MFMA
#pragma unroll
        for (int mt = 0; mt < 4; ++mt) {
            float4 a0 = *(const float4*)&bufp[mt * 512 + rrow + p0];
            float4 a1 = *(const float4*)&bufp[mt * 512 + rrow + p1];
            v8s Ah, Am, Al;
            frag3(a0, a1, Ah, Am, Al);
#pragma unroll
            for (int nt = 0; nt < 4; ++nt) {
                v4f a = acc[mt][nt];
                a = MFMA_BF16(Ah, Bc[nt * 3 + 0], a, 0, 0, 0);
                a = MFMA_BF16(Ah, Bc[nt * 3 + 1], a, 0, 0, 0);
                a = MFMA_BF16(Am, Bc[nt * 3 + 0], a, 0, 0, 0);
                a = MFMA_BF16(Ah, Bc[nt * 3 + 2], a, 0, 0, 0);
                a = MFMA_BF16(Al, Bc[nt * 3 + 0], a, 0, 0, 0);
                a = MFMA_BF16(Am, Bc[nt * 3 + 1], a, 0, 0, 0);
                acc[mt][nt] = a;
            }
        }

        // ---- rotate B (free under full unroll)
        if (ks < NKS - 1) {
#pragma unroll
            for (int c = 0; c < 12; ++c) Bc[c] = Bn[c];
        }
    }

    // ---- cross-wave K reduction (R0 verbatim): red aliases smem[0..16384)
    __syncthreads();                       // all waves done with their slices
    float (*red)[TPB][NEXP] = (float (*)[TPB][NEXP])smem;
    if (wv < 4) {
#pragma unroll
        for (int mt = 0; mt < 4; ++mt)
#pragma unroll
            for (int nt = 0; nt < 4; ++nt)
#pragma unroll
                for (int r = 0; r < 4; ++r) {
                    int tok = 16 * mt + q * 4 + r;
                    int e   = 16 * nt + r16;
                    red[wv][tok][swz_e(tok, e)] = acc[mt][nt][r];
                }
    }
    __syncthreads();
    if (wv >= 4) {
#pragma unroll
        for (int mt = 0; mt < 4; ++mt)
#pragma unroll
            for (int nt = 0; nt < 4; ++nt)
#pragma unroll
                for (int r = 0; r < 4; ++r) {
                    int tok = 16 * mt + q * 4 + r;
                    int e   = 16 * nt + r16;
                    red[wv - 4][tok][swz_e(tok, e)] += acc[mt][nt][r];
                }
    }
    __syncthreads();

    // ---- epilogue: 8 tokens/wave on lanes 0..7 (R0 verbatim)
    if (lane < 8) {
        const int tk = wv * 8 + lane;
        const int t  = tok0 + tk;
        float lg[NEXP];
#pragma unroll
        for (int e = 0; e < NEXP; ++e) {
            int es = swz_e(tk, e);
            lg[e] = ((red[0][tk][es] + red[1][tk][es]) +
                     (red[2][tk][es] + red[3][tk][es])) + Bg[e];
        }
        float* outL = out + (size_t)t * NEXP;
#pragma unroll
        for (int e = 0; e < NEXP; e += 4) {
            float4 v = make_float4(lg[e], lg[e+1], lg[e+2], lg[e+3]);
            *(float4*)(outL + e) = v;
        }
        float mx = lg[0];
#pragma unroll
        for (int e = 1; e < NEXP; ++e) mx = fmaxf(mx, lg[e]);
        float S = 0.f;
#pragma unroll
        for (int e = 0; e < NEXP; ++e) { lg[e] = expf(lg[e] - mx); S += lg[e]; }
#pragma unroll
        for (int e = 0; e < NEXP; ++e) lg[e] = lg[e] / S;

        float v1 = lg[0]; int i1 = 0;
        float v2 = -1.0f; int i2 = 0;
#pragma unroll
        for (int e = 1; e < NEXP; ++e) {
            float rv = lg[e];
            bool g1 = rv > v1;
            bool g2 = rv > v2;
            float nv2 = g1 ? v1 : (g2 ? rv : v2);
            int   ni2 = g1 ? i1 : (g2 ? e  : i2);
            v2 = nv2; i2 = ni2;
            v1 = g1 ? rv : v1;
            i1 = g1 ? e  : i1;
        }
        float den = v1 + v2;
        float w1 = v1 / den, w2 = v2 / den;

        float* outW = out + (size_t)T_TOK * NEXP;
        float* outS = outW + (size_t)T_TOK * 2;
        float* outM = outS + (size_t)T_TOK * 2;
        outW[2*t+0] = w1;        outW[2*t+1] = w2;
        outS[2*t+0] = (float)i1; outS[2*t+1] = (float)i2;

        float* mrow = outM + (size_t)t * 2 * NEXP;
#pragma unroll
        for (int e = 0; e < NEXP; e += 4) {
            float4 a = make_float4(e+0==i1?1.f:0.f, e+1==i1?1.f:0.f,
                                   e+2==i1?1.f:0.f, e+3==i1?1.f:0.f);
            *(float4*)(mrow + e) = a;
            float4 b = make_float4(e+0==i2?1.f:0.f, e+1==i2?1.f:0.f,
                                   e+2==i2?1.f:0.f, e+3==i2?1.f:0.f);
            *(float4*)(mrow + NEXP + e) = b;
        }
    }
}

extern "C" void kernel_launch(void* const* d_in, const int* in_sizes, int n_in,
                              void* d_out, int out_size, void* d_ws, size_t ws_size,
                              hipStream_t stream)
{
    const float* X = (const float*)d_in[0];
    const float* W = (const float*)d_in[1];
    const float* B = (const float*)d_in[2];
    float* out     = (float*)d_out;

    // workspace: packed W fragments, 49152 chunks * 16 B = 768 KiB
    short* Pw = (short*)d_ws;

    hipLaunchKernelGGL(pack_w_kernel, dim3(49152 / 256), dim3(256),
                       0, stream, W, Pw);
    hipLaunchKernelGGL(moe_router_mfma, dim3(T_TOK / TPB), dim3(512),
                       0, stream, X, Pw, B, out);
}